// Round 1
// baseline (778.617 us; speedup 1.0000x reference)
//
#include <hip/hip_runtime.h>
#include <hip/hip_bf16.h>
#include <math.h>

#define B_TOT 8192
#define OBS   4096
#define NG    4
#define GSZ   1024
#define LATD  64
#define HDIM  128   // 2*LAT

// powerset bitmasks in itertools.combinations order (r=1..4)
__constant__ int kMask[15] = {1,2,4,8, 3,5,9,6,10,12, 7,11,13,14, 15};

// ---------------- Encoder GEMM1: h = relu(Xg @ enc_w1 + b1) ----------------
// block: 32 batch rows x 512 cols (c = g*128 + h). 256 thr, 8x8 per thread.
__global__ __launch_bounds__(256) void k_enc1(const float* __restrict__ X,
                                              const float* __restrict__ W1,
                                              const float* __restrict__ B1,
                                              float* __restrict__ H) {
  const int tid  = threadIdx.x;
  const int wid  = tid >> 6;
  const int lane = tid & 63;
  const int r0   = blockIdx.x * 32 + wid * 8;
  const int c0   = lane * 8;          // 0..504
  const int g    = c0 >> 7;           // lane/16
  const int h0   = c0 & 127;

  const float* Wp = W1 + (size_t)g * GSZ * HDIM + h0;  // enc_w1[g][k][h0..]
  const float* Xp = X  + (size_t)r0 * OBS + g;          // Xg[b][g][k] = X[b][4k+g]

  float acc[8][8];
#pragma unroll
  for (int i = 0; i < 8; ++i)
#pragma unroll
    for (int j = 0; j < 8; ++j) acc[i][j] = 0.0f;

#pragma unroll 4
  for (int k = 0; k < GSZ; ++k) {
    const float4 wa = *(const float4*)(Wp + (size_t)k * HDIM);
    const float4 wb = *(const float4*)(Wp + (size_t)k * HDIM + 4);
    float a[8];
#pragma unroll
    for (int i = 0; i < 8; ++i) a[i] = Xp[(size_t)i * OBS + 4 * k];
#pragma unroll
    for (int i = 0; i < 8; ++i) {
      acc[i][0] = fmaf(a[i], wa.x, acc[i][0]);
      acc[i][1] = fmaf(a[i], wa.y, acc[i][1]);
      acc[i][2] = fmaf(a[i], wa.z, acc[i][2]);
      acc[i][3] = fmaf(a[i], wa.w, acc[i][3]);
      acc[i][4] = fmaf(a[i], wb.x, acc[i][4]);
      acc[i][5] = fmaf(a[i], wb.y, acc[i][5]);
      acc[i][6] = fmaf(a[i], wb.z, acc[i][6]);
      acc[i][7] = fmaf(a[i], wb.w, acc[i][7]);
    }
  }

  const float4 ba = *(const float4*)(B1 + c0);      // enc_b1 flat [g*128+h] == c
  const float4 bb = *(const float4*)(B1 + c0 + 4);
#pragma unroll
  for (int i = 0; i < 8; ++i) {
    float4 o1, o2;
    o1.x = fmaxf(acc[i][0] + ba.x, 0.0f);
    o1.y = fmaxf(acc[i][1] + ba.y, 0.0f);
    o1.z = fmaxf(acc[i][2] + ba.z, 0.0f);
    o1.w = fmaxf(acc[i][3] + ba.w, 0.0f);
    o2.x = fmaxf(acc[i][4] + bb.x, 0.0f);
    o2.y = fmaxf(acc[i][5] + bb.y, 0.0f);
    o2.z = fmaxf(acc[i][6] + bb.z, 0.0f);
    o2.w = fmaxf(acc[i][7] + bb.w, 0.0f);
    *(float4*)(H + (size_t)(r0 + i) * 512 + c0)     = o1;
    *(float4*)(H + (size_t)(r0 + i) * 512 + c0 + 4) = o2;
  }
}

// ------------- Encoder GEMM2 + PoE sampling: z = smean + eps/sqrt(tau) ------
__global__ __launch_bounds__(256) void k_enc2_samp(const float* __restrict__ Hin,
                                                   const float* __restrict__ W2,
                                                   const float* __restrict__ B2,
                                                   const float* __restrict__ eps,
                                                   const int*   __restrict__ subset_idx,
                                                   float* __restrict__ Z) {
  __shared__ float mls[32][512];
  const int tid  = threadIdx.x;
  const int wid  = tid >> 6;
  const int lane = tid & 63;
  const int rb   = blockIdx.x * 32;
  const int r0w  = wid * 8;
  const int c0   = lane * 8;
  const int g    = c0 >> 7;
  const int h0   = c0 & 127;

  const float* Wp = W2 + (size_t)g * HDIM * HDIM + h0;   // enc_w2[g][k][h0..]
  const float* Ap = Hin + (size_t)(rb + r0w) * 512 + g * HDIM;

  float acc[8][8];
#pragma unroll
  for (int i = 0; i < 8; ++i)
#pragma unroll
    for (int j = 0; j < 8; ++j) acc[i][j] = 0.0f;

#pragma unroll 4
  for (int k = 0; k < HDIM; ++k) {
    const float4 wa = *(const float4*)(Wp + (size_t)k * HDIM);
    const float4 wb = *(const float4*)(Wp + (size_t)k * HDIM + 4);
    float a[8];
#pragma unroll
    for (int i = 0; i < 8; ++i) a[i] = Ap[(size_t)i * 512 + k];
#pragma unroll
    for (int i = 0; i < 8; ++i) {
      acc[i][0] = fmaf(a[i], wa.x, acc[i][0]);
      acc[i][1] = fmaf(a[i], wa.y, acc[i][1]);
      acc[i][2] = fmaf(a[i], wa.z, acc[i][2]);
      acc[i][3] = fmaf(a[i], wa.w, acc[i][3]);
      acc[i][4] = fmaf(a[i], wb.x, acc[i][4]);
      acc[i][5] = fmaf(a[i], wb.y, acc[i][5]);
      acc[i][6] = fmaf(a[i], wb.z, acc[i][6]);
      acc[i][7] = fmaf(a[i], wb.w, acc[i][7]);
    }
  }

  const float4 ba = *(const float4*)(B2 + c0);
  const float4 bb = *(const float4*)(B2 + c0 + 4);
#pragma unroll
  for (int i = 0; i < 8; ++i) {
    mls[r0w + i][c0 + 0] = acc[i][0] + ba.x;
    mls[r0w + i][c0 + 1] = acc[i][1] + ba.y;
    mls[r0w + i][c0 + 2] = acc[i][2] + ba.z;
    mls[r0w + i][c0 + 3] = acc[i][3] + ba.w;
    mls[r0w + i][c0 + 4] = acc[i][4] + bb.x;
    mls[r0w + i][c0 + 5] = acc[i][5] + bb.y;
    mls[r0w + i][c0 + 6] = acc[i][6] + bb.z;
    mls[r0w + i][c0 + 7] = acc[i][7] + bb.w;
  }
  __syncthreads();

  // 32 rows x 64 latents = 2048 items, 8 per thread; r uniform per wave.
#pragma unroll
  for (int q = 0; q < 8; ++q) {
    const int idx = q * 256 + tid;
    const int r   = idx >> 6;
    const int l   = idx & 63;
    const int m   = kMask[subset_idx[rb + r]];
    float tau = 1.0f, num = 0.0f;
#pragma unroll
    for (int gg = 0; gg < 4; ++gg) {
      if (m & (1 << gg)) {
        const float lv = mls[r][gg * 128 + 64 + l];
        const float mu = mls[r][gg * 128 + l];
        const float t  = expf(-lv);
        tau += t;
        num = fmaf(t, mu, num);
      }
    }
    const float zv = num / tau + eps[(size_t)(rb + r) * LATD + l] * rsqrtf(tau);
    Z[(size_t)(rb + r) * LATD + l] = zv;
  }
}

// ---------------- Decoder GEMM1: hd = relu(z @ dec_w1 + b1) -----------------
// block: 32 rows x 256 cols (c = g*64 + m), thread 8x4.
__global__ __launch_bounds__(256) void k_dec1(const float* __restrict__ Z,
                                              const float* __restrict__ W,
                                              const float* __restrict__ Bb,
                                              float* __restrict__ Hd) {
  const int tid  = threadIdx.x;
  const int wid  = tid >> 6;
  const int lane = tid & 63;
  const int r0   = blockIdx.x * 32 + wid * 8;
  const int c0   = lane * 4;      // 0..252
  const int g    = c0 >> 6;
  const int m0   = c0 & 63;

  const float* Wp = W + (size_t)g * LATD * LATD + m0;  // dec_w1[g][k][m0..]
  const float* Ap = Z + (size_t)r0 * LATD;

  float acc[8][4];
#pragma unroll
  for (int i = 0; i < 8; ++i)
#pragma unroll
    for (int j = 0; j < 4; ++j) acc[i][j] = 0.0f;

#pragma unroll 4
  for (int k = 0; k < LATD; ++k) {
    const float4 w = *(const float4*)(Wp + (size_t)k * LATD);
    float a[8];
#pragma unroll
    for (int i = 0; i < 8; ++i) a[i] = Ap[(size_t)i * LATD + k];
#pragma unroll
    for (int i = 0; i < 8; ++i) {
      acc[i][0] = fmaf(a[i], w.x, acc[i][0]);
      acc[i][1] = fmaf(a[i], w.y, acc[i][1]);
      acc[i][2] = fmaf(a[i], w.z, acc[i][2]);
      acc[i][3] = fmaf(a[i], w.w, acc[i][3]);
    }
  }

  const float4 ba = *(const float4*)(Bb + c0);  // dec_b1 flat [g*64+m] == c
#pragma unroll
  for (int i = 0; i < 8; ++i) {
    float4 o;
    o.x = fmaxf(acc[i][0] + ba.x, 0.0f);
    o.y = fmaxf(acc[i][1] + ba.y, 0.0f);
    o.z = fmaxf(acc[i][2] + ba.z, 0.0f);
    o.w = fmaxf(acc[i][3] + ba.w, 0.0f);
    *(float4*)(Hd + (size_t)(r0 + i) * 256 + c0) = o;
  }
}

// ------------- Decoder GEMM2 + scatter: recon[b][4o+g] = hd@W2 + b2 ---------
// grid.y = 8 col-blocks: g = ci>>1, o-range = (ci&1)*512..+512
__global__ __launch_bounds__(256) void k_dec2(const float* __restrict__ Hd,
                                              const float* __restrict__ W,
                                              const float* __restrict__ Bb,
                                              float* __restrict__ Out) {
  const int tid  = threadIdx.x;
  const int wid  = tid >> 6;
  const int lane = tid & 63;
  const int r0   = blockIdx.x * 32 + wid * 8;
  const int ci   = blockIdx.y;
  const int g    = ci >> 1;
  const int o0   = (ci & 1) * 512 + lane * 8;   // 0..1016

  const float* Wp = W + (size_t)g * LATD * GSZ + o0;   // dec_w2[g][k][o0..]
  const float* Ap = Hd + (size_t)r0 * 256 + g * LATD;

  float acc[8][8];
#pragma unroll
  for (int i = 0; i < 8; ++i)
#pragma unroll
    for (int j = 0; j < 8; ++j) acc[i][j] = 0.0f;

#pragma unroll 4
  for (int k = 0; k < LATD; ++k) {
    const float4 wa = *(const float4*)(Wp + (size_t)k * GSZ);
    const float4 wb = *(const float4*)(Wp + (size_t)k * GSZ + 4);
    float a[8];
#pragma unroll
    for (int i = 0; i < 8; ++i) a[i] = Ap[(size_t)i * 256 + k];
#pragma unroll
    for (int i = 0; i < 8; ++i) {
      acc[i][0] = fmaf(a[i], wa.x, acc[i][0]);
      acc[i][1] = fmaf(a[i], wa.y, acc[i][1]);
      acc[i][2] = fmaf(a[i], wa.z, acc[i][2]);
      acc[i][3] = fmaf(a[i], wa.w, acc[i][3]);
      acc[i][4] = fmaf(a[i], wb.x, acc[i][4]);
      acc[i][5] = fmaf(a[i], wb.y, acc[i][5]);
      acc[i][6] = fmaf(a[i], wb.z, acc[i][6]);
      acc[i][7] = fmaf(a[i], wb.w, acc[i][7]);
    }
  }

  const float4 ba = *(const float4*)(Bb + (size_t)g * GSZ + o0);
  const float4 bb = *(const float4*)(Bb + (size_t)g * GSZ + o0 + 4);
  const float bias[8] = {ba.x, ba.y, ba.z, ba.w, bb.x, bb.y, bb.z, bb.w};
#pragma unroll
  for (int i = 0; i < 8; ++i) {
    float* orow = Out + (size_t)(r0 + i) * OBS + g;
#pragma unroll
    for (int j = 0; j < 8; ++j) {
      orow[4 * (o0 + j)] = acc[i][j] + bias[j];
    }
  }
}

extern "C" void kernel_launch(void* const* d_in, const int* in_sizes, int n_in,
                              void* d_out, int out_size, void* d_ws, size_t ws_size,
                              hipStream_t stream) {
  const float* X          = (const float*)d_in[0];
  const float* eps        = (const float*)d_in[1];
  const int*   subset_idx = (const int*)  d_in[2];
  const float* enc_w1     = (const float*)d_in[3];
  const float* enc_b1     = (const float*)d_in[4];
  const float* enc_w2     = (const float*)d_in[5];
  const float* enc_b2     = (const float*)d_in[6];
  const float* dec_w1     = (const float*)d_in[7];
  const float* dec_b1     = (const float*)d_in[8];
  const float* dec_w2     = (const float*)d_in[9];
  const float* dec_b2     = (const float*)d_in[10];
  float* out = (float*)d_out;

  float* ws = (float*)d_ws;
  float* h  = ws;                                   // B*512
  float* z  = ws + (size_t)B_TOT * 512;             // B*64
  float* hd = z  + (size_t)B_TOT * LATD;            // B*256

  k_enc1<<<dim3(B_TOT / 32), dim3(256), 0, stream>>>(X, enc_w1, enc_b1, h);
  k_enc2_samp<<<dim3(B_TOT / 32), dim3(256), 0, stream>>>(h, enc_w2, enc_b2,
                                                          eps, subset_idx, z);
  k_dec1<<<dim3(B_TOT / 32), dim3(256), 0, stream>>>(z, dec_w1, dec_b1, hd);
  k_dec2<<<dim3(B_TOT / 32, 8), dim3(256), 0, stream>>>(hd, dec_w2, dec_b2, out);
}

// Round 2
// 200.594 us; speedup vs baseline: 3.8815x; 3.8815x over previous
//
#include <hip/hip_runtime.h>
#include <hip/hip_bf16.h>
#include <math.h>

#define B_TOT 8192
#define OBS   4096
#define NG    4
#define GSZ   1024
#define LATD  64
#define HDIM  128

typedef __attribute__((ext_vector_type(8))) short   short8_t;
typedef __attribute__((ext_vector_type(8))) unsigned short ushort8_t;
typedef __attribute__((ext_vector_type(4))) float   float4_t;

__constant__ int kMask[15] = {1,2,4,8, 3,5,9,6,10,12, 7,11,13,14, 15};

static __device__ __forceinline__ unsigned short f2b(float x) {
  __hip_bfloat16 b = __float2bfloat16(x);
  return *reinterpret_cast<unsigned short*>(&b);
}
static __device__ __forceinline__ unsigned int pack2(float lo, float hi) {
  return (unsigned int)f2b(lo) | ((unsigned int)f2b(hi) << 16);
}

// ---------------- weight prep: transpose + bf16 ----------------
// W1t[g][h][k] = enc_w1[g][k][h]   (4,128,1024)
__global__ __launch_bounds__(256) void prep_w1t(const float* __restrict__ W,
                                                unsigned short* __restrict__ Wt) {
  const int o = blockIdx.x * 256 + threadIdx.x;      // 524288 total
  const int g = o >> 17, rem = o & 131071;
  const int h = rem >> 10, k = rem & 1023;
  Wt[o] = f2b(W[g * 131072 + k * 128 + h]);
}
// W4t[g][o][k] = dec_w2[g][k][o]   (4,1024,64)
__global__ __launch_bounds__(256) void prep_w4t(const float* __restrict__ W,
                                                unsigned short* __restrict__ Wt) {
  const int idx = blockIdx.x * 256 + threadIdx.x;    // 262144 total
  const int g = idx >> 16, rem = idx & 65535;
  const int oc = rem >> 6, k = rem & 63;
  Wt[idx] = f2b(W[g * 65536 + k * 1024 + oc]);
}

// ---------------- enc1 MFMA: h = relu(Xg @ enc_w1 + b1), fp32 out ----------
// 256 blocks x 512 thr. Block: 32 rows x 512 cols. Wave w: g=w>>1, hh=(w&1)*64.
// Wave tile 32r x 64h = 2x4 frags of 16x16. K-loop: 32 steps of 32.
__global__ __launch_bounds__(512) void k_enc1(const float* __restrict__ X,
                                              const unsigned short* __restrict__ W1t,
                                              const float* __restrict__ B1,
                                              float* __restrict__ H) {
  __shared__ unsigned short lA[4][32][40];   // pad 8 -> 80B rows
  __shared__ unsigned short lB[4][128][40];

  const int tid  = threadIdx.x;
  const int w    = tid >> 6;
  const int l    = tid & 63;
  const int g    = w >> 1;
  const int hh   = (w & 1) * 64;
  const int r0b  = blockIdx.x * 32;
  const int l15  = l & 15;
  const int oct  = l >> 4;

  float4_t acc[2][4];
#pragma unroll
  for (int i = 0; i < 2; ++i)
#pragma unroll
    for (int j = 0; j < 4; ++j) acc[i][j] = (float4_t){0.f, 0.f, 0.f, 0.f};

  // staging indices (hoisted)
  const int sr  = tid >> 4;            // 0..31
  const int sc0 = (tid & 15) * 8;      // 0..120
  const int skk = (tid & 15) * 2;

  for (int step = 0; step < 32; ++step) {
    // stage A: X[r0b+sr][step*128 + sc0 .. +7] -> de-interleave into g planes
    {
      const float* xp = X + (size_t)(r0b + sr) * OBS + step * 128 + sc0;
      const float4 f0 = *(const float4*)(xp);
      const float4 f1 = *(const float4*)(xp + 4);
      const float a0[4] = {f0.x, f0.y, f0.z, f0.w};
      const float a1[4] = {f1.x, f1.y, f1.z, f1.w};
#pragma unroll
      for (int gg = 0; gg < 4; ++gg) {
        *(unsigned int*)((char*)&lA[gg][sr][0] + skk * 2) = pack2(a0[gg], a1[gg]);
      }
    }
    // stage B: W1t slice [512 rows][32 k]
#pragma unroll
    for (int i = 0; i < 4; ++i) {
      const int q   = tid + i * 512;
      const int row = q >> 2;            // 0..511 = g*128+h
      const int ko  = (q & 3) * 8;
      const ushort8_t v = *(const ushort8_t*)(W1t + (size_t)row * 1024 + step * 32 + ko);
      *(ushort8_t*)((char*)&lB[0][0][0] + row * 80 + ko * 2) = v;
    }
    __syncthreads();

    short8_t af[2], bf[4];
#pragma unroll
    for (int mi = 0; mi < 2; ++mi)
      af[mi] = *(const short8_t*)((char*)&lA[g][0][0] + (mi * 16 + l15) * 80 + oct * 16);
#pragma unroll
    for (int ni = 0; ni < 4; ++ni)
      bf[ni] = *(const short8_t*)((char*)&lB[g][0][0] + (hh + ni * 16 + l15) * 80 + oct * 16);
#pragma unroll
    for (int mi = 0; mi < 2; ++mi)
#pragma unroll
      for (int ni = 0; ni < 4; ++ni)
        acc[mi][ni] = __builtin_amdgcn_mfma_f32_16x16x32_bf16(af[mi], bf[ni], acc[mi][ni], 0, 0, 0);
    __syncthreads();
  }

  // epilogue: bias + relu + store fp32
#pragma unroll
  for (int ni = 0; ni < 4; ++ni) {
    const int col = g * 128 + hh + ni * 16 + l15;
    const float b = B1[col];
#pragma unroll
    for (int mi = 0; mi < 2; ++mi) {
      const int rbase = r0b + mi * 16 + oct * 4;
#pragma unroll
      for (int j = 0; j < 4; ++j)
        H[(size_t)(rbase + j) * 512 + col] = fmaxf(acc[mi][ni][j] + b, 0.0f);
    }
  }
}

// ------------- enc2 + PoE sampling (fp32 vector, 512 blocks) ---------------
// block: 16 rows x 512 cols, 256 thr, thread tile 4x8.
__global__ __launch_bounds__(256) void k_enc2_samp(const float* __restrict__ Hin,
                                                   const float* __restrict__ W2,
                                                   const float* __restrict__ B2,
                                                   const float* __restrict__ eps,
                                                   const int*   __restrict__ subset_idx,
                                                   float* __restrict__ Z) {
  __shared__ float mls[16][512];
  const int tid  = threadIdx.x;
  const int wid  = tid >> 6;
  const int lane = tid & 63;
  const int rb   = blockIdx.x * 16;
  const int r0w  = wid * 4;
  const int c0   = lane * 8;
  const int g    = c0 >> 7;
  const int h0   = c0 & 127;

  const float* Wp = W2 + (size_t)g * HDIM * HDIM + h0;
  const float* Ap = Hin + (size_t)(rb + r0w) * 512 + g * HDIM;

  float acc[4][8];
#pragma unroll
  for (int i = 0; i < 4; ++i)
#pragma unroll
    for (int j = 0; j < 8; ++j) acc[i][j] = 0.0f;

#pragma unroll 4
  for (int k = 0; k < HDIM; ++k) {
    const float4 wa = *(const float4*)(Wp + (size_t)k * HDIM);
    const float4 wb = *(const float4*)(Wp + (size_t)k * HDIM + 4);
    float a[4];
#pragma unroll
    for (int i = 0; i < 4; ++i) a[i] = Ap[(size_t)i * 512 + k];
#pragma unroll
    for (int i = 0; i < 4; ++i) {
      acc[i][0] = fmaf(a[i], wa.x, acc[i][0]);
      acc[i][1] = fmaf(a[i], wa.y, acc[i][1]);
      acc[i][2] = fmaf(a[i], wa.z, acc[i][2]);
      acc[i][3] = fmaf(a[i], wa.w, acc[i][3]);
      acc[i][4] = fmaf(a[i], wb.x, acc[i][4]);
      acc[i][5] = fmaf(a[i], wb.y, acc[i][5]);
      acc[i][6] = fmaf(a[i], wb.z, acc[i][6]);
      acc[i][7] = fmaf(a[i], wb.w, acc[i][7]);
    }
  }

#pragma unroll
  for (int i = 0; i < 4; ++i)
#pragma unroll
    for (int j = 0; j < 8; ++j)
      mls[r0w + i][c0 + j] = acc[i][j] + B2[c0 + j];
  __syncthreads();

#pragma unroll
  for (int q = 0; q < 4; ++q) {
    const int idx = q * 256 + tid;
    const int r   = idx >> 6;
    const int ll  = idx & 63;
    const int m   = kMask[subset_idx[rb + r]];
    float tau = 1.0f, num = 0.0f;
#pragma unroll
    for (int gg = 0; gg < 4; ++gg) {
      if (m & (1 << gg)) {
        const float lv = mls[r][gg * 128 + 64 + ll];
        const float mu = mls[r][gg * 128 + ll];
        const float t  = expf(-lv);
        tau += t;
        num = fmaf(t, mu, num);
      }
    }
    Z[(size_t)(rb + r) * LATD + ll] =
        num / tau + eps[(size_t)(rb + r) * LATD + ll] * rsqrtf(tau);
  }
}

// ---------------- dec1 (fp32 vector, 512 blocks) -> hd in bf16 -------------
// block: 16 rows x 256 cols, thread tile 4x4.
__global__ __launch_bounds__(256) void k_dec1(const float* __restrict__ Z,
                                              const float* __restrict__ W,
                                              const float* __restrict__ Bb,
                                              unsigned short* __restrict__ Hd) {
  const int tid  = threadIdx.x;
  const int wid  = tid >> 6;
  const int lane = tid & 63;
  const int r0   = blockIdx.x * 16 + wid * 4;
  const int c0   = lane * 4;
  const int g    = c0 >> 6;
  const int m0   = c0 & 63;

  const float* Wp = W + (size_t)g * LATD * LATD + m0;
  const float* Ap = Z + (size_t)r0 * LATD;

  float acc[4][4];
#pragma unroll
  for (int i = 0; i < 4; ++i)
#pragma unroll
    for (int j = 0; j < 4; ++j) acc[i][j] = 0.0f;

#pragma unroll 4
  for (int k = 0; k < LATD; ++k) {
    const float4 wv = *(const float4*)(Wp + (size_t)k * LATD);
    float a[4];
#pragma unroll
    for (int i = 0; i < 4; ++i) a[i] = Ap[(size_t)i * LATD + k];
#pragma unroll
    for (int i = 0; i < 4; ++i) {
      acc[i][0] = fmaf(a[i], wv.x, acc[i][0]);
      acc[i][1] = fmaf(a[i], wv.y, acc[i][1]);
      acc[i][2] = fmaf(a[i], wv.z, acc[i][2]);
      acc[i][3] = fmaf(a[i], wv.w, acc[i][3]);
    }
  }

  const float4 ba = *(const float4*)(Bb + c0);
#pragma unroll
  for (int i = 0; i < 4; ++i) {
    ushort4 o;
    o.x = f2b(fmaxf(acc[i][0] + ba.x, 0.0f));
    o.y = f2b(fmaxf(acc[i][1] + ba.y, 0.0f));
    o.z = f2b(fmaxf(acc[i][2] + ba.z, 0.0f));
    o.w = f2b(fmaxf(acc[i][3] + ba.w, 0.0f));
    *(ushort4*)(Hd + (size_t)(r0 + i) * 256 + c0) = o;
  }
}

// ---------------- dec2 MFMA + scatter: out[b][4o+g] ------------------------
// grid (256, 16), 512 thr. Block: 32 rows x (4g x 64 o). Wave: g=w>>1,
// ohh=(w&1)*32; wave tile 32r x 32o = 2x2 frags; K=64 (2 MFMA k-steps).
__global__ __launch_bounds__(512) void k_dec2(const unsigned short* __restrict__ Hd,
                                              const unsigned short* __restrict__ W4t,
                                              const float* __restrict__ Bb,
                                              float* __restrict__ Out) {
  __shared__ unsigned short lA[4][32][72];   // 64 k + 8 pad -> 144B rows
  __shared__ unsigned short lB[4][64][72];

  const int tid = threadIdx.x;
  const int w   = tid >> 6;
  const int l   = tid & 63;
  const int g   = w >> 1;
  const int ohh = (w & 1) * 32;
  const int r0  = blockIdx.x * 32;
  const int ob  = blockIdx.y * 64;
  const int l15 = l & 15;
  const int oct = l >> 4;

  // stage A: hd[r0..r0+31][0..255]
#pragma unroll
  for (int i = 0; i < 2; ++i) {
    const int q   = tid + i * 512;     // 1024 chunks
    const int row = q >> 5;            // 0..31
    const int off = (q & 31) * 8;      // 0..248
    const int gg  = off >> 6, k = off & 63;
    const ushort8_t v = *(const ushort8_t*)(Hd + (size_t)(r0 + row) * 256 + off);
    *(ushort8_t*)((char*)&lA[gg][row][0] + k * 2) = v;
  }
  // stage B: W4t[g][ob..ob+63][0..63]
#pragma unroll
  for (int i = 0; i < 4; ++i) {
    const int q   = tid + i * 512;     // 2048 chunks
    const int row = q >> 3;            // 0..255 = g*64+o
    const int gg  = row >> 6, o = row & 63;
    const int ko  = (q & 7) * 8;
    const ushort8_t v = *(const ushort8_t*)(W4t + (size_t)(gg * 1024 + ob + o) * 64 + ko);
    *(ushort8_t*)((char*)&lB[0][0][0] + row * 144 + ko * 2) = v;
  }
  __syncthreads();

  float4_t acc[2][2];
#pragma unroll
  for (int i = 0; i < 2; ++i)
#pragma unroll
    for (int j = 0; j < 2; ++j) acc[i][j] = (float4_t){0.f, 0.f, 0.f, 0.f};

#pragma unroll
  for (int ks = 0; ks < 2; ++ks) {
    short8_t af[2], bf[2];
#pragma unroll
    for (int mi = 0; mi < 2; ++mi)
      af[mi] = *(const short8_t*)((char*)&lA[g][0][0] + (mi * 16 + l15) * 144 + (ks * 32 + oct * 8) * 2);
#pragma unroll
    for (int ni = 0; ni < 2; ++ni)
      bf[ni] = *(const short8_t*)((char*)&lB[g][0][0] + (ohh + ni * 16 + l15) * 144 + (ks * 32 + oct * 8) * 2);
#pragma unroll
    for (int mi = 0; mi < 2; ++mi)
#pragma unroll
      for (int ni = 0; ni < 2; ++ni)
        acc[mi][ni] = __builtin_amdgcn_mfma_f32_16x16x32_bf16(af[mi], bf[ni], acc[mi][ni], 0, 0, 0);
  }

#pragma unroll
  for (int ni = 0; ni < 2; ++ni) {
    const int og = ob + ohh + ni * 16 + l15;
    const float b = Bb[g * 1024 + og];
#pragma unroll
    for (int mi = 0; mi < 2; ++mi) {
      const int rbase = r0 + mi * 16 + oct * 4;
#pragma unroll
      for (int j = 0; j < 4; ++j)
        Out[(size_t)(rbase + j) * OBS + 4 * og + g] = acc[mi][ni][j] + b;
    }
  }
}

extern "C" void kernel_launch(void* const* d_in, const int* in_sizes, int n_in,
                              void* d_out, int out_size, void* d_ws, size_t ws_size,
                              hipStream_t stream) {
  const float* X          = (const float*)d_in[0];
  const float* eps        = (const float*)d_in[1];
  const int*   subset_idx = (const int*)  d_in[2];
  const float* enc_w1     = (const float*)d_in[3];
  const float* enc_b1     = (const float*)d_in[4];
  const float* enc_w2     = (const float*)d_in[5];
  const float* enc_b2     = (const float*)d_in[6];
  const float* dec_w1     = (const float*)d_in[7];
  const float* dec_b1     = (const float*)d_in[8];
  const float* dec_w2     = (const float*)d_in[9];
  const float* dec_b2     = (const float*)d_in[10];
  float* out = (float*)d_out;

  char* wsb = (char*)d_ws;
  float*          h   = (float*)wsb;                         // 16 MB
  float*          z   = (float*)(wsb + (16u << 20));         // 2 MB
  unsigned short* hd  = (unsigned short*)(wsb + (18u << 20));// 4 MB
  unsigned short* W1t = (unsigned short*)(wsb + (22u << 20));// 1 MB
  unsigned short* W4t = (unsigned short*)(wsb + (23u << 20));// 0.5 MB

  prep_w1t<<<2048, 256, 0, stream>>>(enc_w1, W1t);
  prep_w4t<<<1024, 256, 0, stream>>>(dec_w2, W4t);
  k_enc1<<<256, 512, 0, stream>>>(X, W1t, enc_b1, h);
  k_enc2_samp<<<512, 256, 0, stream>>>(h, enc_w2, enc_b2, eps, subset_idx, z);
  k_dec1<<<512, 256, 0, stream>>>(z, dec_w1, dec_b1, hd);
  k_dec2<<<dim3(256, 16), 512, 0, stream>>>(hd, W4t, dec_b2, out);
}

// Round 3
// 144.132 us; speedup vs baseline: 5.4021x; 1.3917x over previous
//
#include <hip/hip_runtime.h>
#include <hip/hip_bf16.h>
#include <math.h>

#define B_TOT 8192
#define OBS   4096
#define NG    4
#define GSZ   1024
#define LATD  64
#define HDIM  128

typedef __attribute__((ext_vector_type(8))) short   short8_t;
typedef __attribute__((ext_vector_type(8))) unsigned short ushort8_t;
typedef __attribute__((ext_vector_type(4))) float   float4_t;

__constant__ int kMask[15] = {1,2,4,8, 3,5,9,6,10,12, 7,11,13,14, 15};

static __device__ __forceinline__ unsigned short f2b(float x) {
  __hip_bfloat16 b = __float2bfloat16(x);
  return *reinterpret_cast<unsigned short*>(&b);
}
static __device__ __forceinline__ unsigned int pack2(float lo, float hi) {
  return (unsigned int)f2b(lo) | ((unsigned int)f2b(hi) << 16);
}

// ---------------- weight prep: transpose + bf16 ----------------
// W1t[(g*128+h)*1024 + k] = enc_w1[g][k][h]
__global__ __launch_bounds__(256) void prep_w1t(const float* __restrict__ W,
                                                unsigned short* __restrict__ Wt) {
  const int o = blockIdx.x * 256 + threadIdx.x;      // 524288
  const int g = o >> 17, rem = o & 131071;
  const int h = rem >> 10, k = rem & 1023;
  Wt[o] = f2b(W[g * 131072 + k * 128 + h]);
}
// W2t[(g*128+o)*128 + k] = enc_w2[g][k][o]
__global__ __launch_bounds__(256) void prep_w2t(const float* __restrict__ W,
                                                unsigned short* __restrict__ Wt) {
  const int idx = blockIdx.x * 256 + threadIdx.x;    // 65536
  const int g = idx >> 14, rem = idx & 16383;
  const int o = rem >> 7, k = rem & 127;
  Wt[idx] = f2b(W[g * 16384 + k * 128 + o]);
}
// W4t[(g*1024+o)*64 + k] = dec_w2[g][k][o]
__global__ __launch_bounds__(256) void prep_w4t(const float* __restrict__ W,
                                                unsigned short* __restrict__ Wt) {
  const int idx = blockIdx.x * 256 + threadIdx.x;    // 262144
  const int g = idx >> 16, rem = idx & 65535;
  const int o = rem >> 6, k = rem & 63;
  Wt[idx] = f2b(W[g * 65536 + k * 1024 + o]);
}

// ---------------- enc1: Hbf = relu(Xg @ enc_w1 + b1), bf16 out -------------
// 256 blocks x 512 thr. Block: 32 rows x 512 cols (4g x 2hh waves).
// A (X de-interleave) via double-buffered LDS; B direct global (L2).
__global__ __launch_bounds__(512) void k_enc1(const float* __restrict__ X,
                                              const unsigned short* __restrict__ W1t,
                                              const float* __restrict__ B1,
                                              unsigned short* __restrict__ Hbf) {
  __shared__ unsigned short lA[2][4][32][40];   // 80B rows (conflict-free, measured)

  const int tid = threadIdx.x;
  const int w   = tid >> 6;
  const int l   = tid & 63;
  const int g   = w >> 1;
  const int hh  = (w & 1) * 64;
  const int r0b = blockIdx.x * 32;
  const int l15 = l & 15;
  const int oct = l >> 4;

  const int sr  = tid >> 4;         // stage row 0..31
  const int skk = tid & 15;         // stage k-pair 0..15

  float4_t acc[2][4];
#pragma unroll
  for (int i = 0; i < 2; ++i)
#pragma unroll
    for (int j = 0; j < 4; ++j) acc[i][j] = (float4_t){0.f, 0.f, 0.f, 0.f};

  // prologue stage step 0 into buf 0
  {
    const float* xp = X + (size_t)(r0b + sr) * OBS + skk * 8;
    const float4 f0 = *(const float4*)(xp);
    const float4 f1 = *(const float4*)(xp + 4);
    const float a0[4] = {f0.x, f0.y, f0.z, f0.w};
    const float a1[4] = {f1.x, f1.y, f1.z, f1.w};
#pragma unroll
    for (int gg = 0; gg < 4; ++gg)
      *(unsigned int*)(&lA[0][gg][sr][skk * 2]) = pack2(a0[gg], a1[gg]);
  }
  __syncthreads();

  for (int s = 0; s < 32; ++s) {
    const int cur = s & 1;
    short8_t af[2], bf[4];
#pragma unroll
    for (int mi = 0; mi < 2; ++mi)
      af[mi] = *(const short8_t*)((const char*)&lA[cur][g][0][0] +
                                  (mi * 16 + l15) * 80 + oct * 16);
#pragma unroll
    for (int ni = 0; ni < 4; ++ni)
      bf[ni] = *(const short8_t*)(W1t +
                (size_t)(g * 128 + hh + ni * 16 + l15) * 1024 + s * 32 + oct * 8);

    if (s < 31) {   // stage step s+1 into other buffer
      const float* xp = X + (size_t)(r0b + sr) * OBS + (s + 1) * 128 + skk * 8;
      const float4 f0 = *(const float4*)(xp);
      const float4 f1 = *(const float4*)(xp + 4);
      const float a0[4] = {f0.x, f0.y, f0.z, f0.w};
      const float a1[4] = {f1.x, f1.y, f1.z, f1.w};
#pragma unroll
      for (int gg = 0; gg < 4; ++gg)
        *(unsigned int*)(&lA[cur ^ 1][gg][sr][skk * 2]) = pack2(a0[gg], a1[gg]);
    }

#pragma unroll
    for (int mi = 0; mi < 2; ++mi)
#pragma unroll
      for (int ni = 0; ni < 4; ++ni)
        acc[mi][ni] = __builtin_amdgcn_mfma_f32_16x16x32_bf16(af[mi], bf[ni], acc[mi][ni], 0, 0, 0);
    __syncthreads();
  }

#pragma unroll
  for (int ni = 0; ni < 4; ++ni) {
    const int col = g * 128 + hh + ni * 16 + l15;
    const float b = B1[col];
#pragma unroll
    for (int mi = 0; mi < 2; ++mi) {
      const int rbase = r0b + mi * 16 + oct * 4;
#pragma unroll
      for (int j = 0; j < 4; ++j)
        Hbf[(size_t)(rbase + j) * 512 + col] = f2b(fmaxf(acc[mi][ni][j] + b, 0.0f));
    }
  }
}

// ------------- enc2 (MFMA) + PoE sampling ----------------------------------
// 256 blocks x 512 thr. Block: 32 rows x 512 cols. K=128 in 4 steps.
struct Enc2Lds {
  union {
    struct { unsigned short A[32][520]; unsigned short B[512][40]; } st;
    float mls[32][516];
  };
};
__global__ __launch_bounds__(512) void k_enc2_samp(const unsigned short* __restrict__ Hbf,
                                                   const unsigned short* __restrict__ W2t,
                                                   const float* __restrict__ B2,
                                                   const float* __restrict__ eps,
                                                   const int*   __restrict__ subset_idx,
                                                   float* __restrict__ Z) {
  __shared__ Enc2Lds u;
  const int tid = threadIdx.x;
  const int w   = tid >> 6;
  const int l   = tid & 63;
  const int g   = w >> 1;
  const int hh  = (w & 1) * 64;
  const int rb  = blockIdx.x * 32;
  const int l15 = l & 15;
  const int oct = l >> 4;

  // stage A once: Hbf[rb..rb+31][0..511]
#pragma unroll
  for (int i = 0; i < 4; ++i) {
    const int q = tid + i * 512;
    const int row = q >> 6, co = (q & 63) * 8;
    *(ushort8_t*)&u.st.A[row][co] =
        *(const ushort8_t*)(Hbf + (size_t)(rb + row) * 512 + co);
  }

  float4_t acc[2][4];
#pragma unroll
  for (int i = 0; i < 2; ++i)
#pragma unroll
    for (int j = 0; j < 4; ++j) acc[i][j] = (float4_t){0.f, 0.f, 0.f, 0.f};

  for (int ks = 0; ks < 4; ++ks) {
    // stage B slice: [512 rows][32 k]
#pragma unroll
    for (int i = 0; i < 4; ++i) {
      const int q = tid + i * 512;
      const int row = q >> 2, ko = (q & 3) * 8;
      *(ushort8_t*)&u.st.B[row][ko] =
          *(const ushort8_t*)(W2t + (size_t)row * 128 + ks * 32 + ko);
    }
    __syncthreads();

    short8_t af[2], bf[4];
#pragma unroll
    for (int mi = 0; mi < 2; ++mi)
      af[mi] = *(const short8_t*)&u.st.A[mi * 16 + l15][g * 128 + ks * 32 + oct * 8];
#pragma unroll
    for (int ni = 0; ni < 4; ++ni)
      bf[ni] = *(const short8_t*)&u.st.B[g * 128 + hh + ni * 16 + l15][oct * 8];
#pragma unroll
    for (int mi = 0; mi < 2; ++mi)
#pragma unroll
      for (int ni = 0; ni < 4; ++ni)
        acc[mi][ni] = __builtin_amdgcn_mfma_f32_16x16x32_bf16(af[mi], bf[ni], acc[mi][ni], 0, 0, 0);
    __syncthreads();
  }

  // ml -> LDS (fp32), overlaying staging buffers (post-barrier safe)
#pragma unroll
  for (int ni = 0; ni < 4; ++ni) {
    const int col = g * 128 + hh + ni * 16 + l15;
    const float b = B2[col];
#pragma unroll
    for (int mi = 0; mi < 2; ++mi)
#pragma unroll
      for (int j = 0; j < 4; ++j)
        u.mls[mi * 16 + oct * 4 + j][col] = acc[mi][ni][j] + b;
  }
  __syncthreads();

  // PoE + reparameterize: 32 rows x 64 latents
#pragma unroll
  for (int q = 0; q < 4; ++q) {
    const int idx = q * 512 + tid;
    const int r   = idx >> 6;
    const int ll  = idx & 63;
    const int m   = kMask[subset_idx[rb + r]];
    float tau = 1.0f, num = 0.0f;
#pragma unroll
    for (int gg = 0; gg < 4; ++gg) {
      if (m & (1 << gg)) {
        const float lv = u.mls[r][gg * 128 + 64 + ll];
        const float mu = u.mls[r][gg * 128 + ll];
        const float t  = expf(-lv);
        tau += t;
        num = fmaf(t, mu, num);
      }
    }
    Z[(size_t)(rb + r) * LATD + ll] =
        num / tau + eps[(size_t)(rb + r) * LATD + ll] * rsqrtf(tau);
  }
}

// ---------------- dec1 (fp32 vector) -> hd bf16 ----------------------------
__global__ __launch_bounds__(256) void k_dec1(const float* __restrict__ Z,
                                              const float* __restrict__ W,
                                              const float* __restrict__ Bb,
                                              unsigned short* __restrict__ Hd) {
  const int tid  = threadIdx.x;
  const int wid  = tid >> 6;
  const int lane = tid & 63;
  const int r0   = blockIdx.x * 16 + wid * 4;
  const int c0   = lane * 4;
  const int g    = c0 >> 6;
  const int m0   = c0 & 63;

  const float* Wp = W + (size_t)g * LATD * LATD + m0;
  const float* Ap = Z + (size_t)r0 * LATD;

  float acc[4][4];
#pragma unroll
  for (int i = 0; i < 4; ++i)
#pragma unroll
    for (int j = 0; j < 4; ++j) acc[i][j] = 0.0f;

#pragma unroll 4
  for (int k = 0; k < LATD; ++k) {
    const float4 wv = *(const float4*)(Wp + (size_t)k * LATD);
    float a[4];
#pragma unroll
    for (int i = 0; i < 4; ++i) a[i] = Ap[(size_t)i * LATD + k];
#pragma unroll
    for (int i = 0; i < 4; ++i) {
      acc[i][0] = fmaf(a[i], wv.x, acc[i][0]);
      acc[i][1] = fmaf(a[i], wv.y, acc[i][1]);
      acc[i][2] = fmaf(a[i], wv.z, acc[i][2]);
      acc[i][3] = fmaf(a[i], wv.w, acc[i][3]);
    }
  }

  const float4 ba = *(const float4*)(Bb + c0);
#pragma unroll
  for (int i = 0; i < 4; ++i) {
    ushort4 o;
    o.x = f2b(fmaxf(acc[i][0] + ba.x, 0.0f));
    o.y = f2b(fmaxf(acc[i][1] + ba.y, 0.0f));
    o.z = f2b(fmaxf(acc[i][2] + ba.z, 0.0f));
    o.w = f2b(fmaxf(acc[i][3] + ba.w, 0.0f));
    *(ushort4*)(Hd + (size_t)(r0 + i) * 256 + c0) = o;
  }
}

// ---------------- dec2: direct-global MFMA + coalesced epilogue ------------
// grid (256,16) x 512 thr. Block: 32 rows x 256 contiguous out cols
// (= 4 groups x 64 o at ob=by*64). Wave: g=w>>1, ohh=(w&1)*32.
__global__ __launch_bounds__(512) void k_dec2(const unsigned short* __restrict__ Hd,
                                              const unsigned short* __restrict__ W4t,
                                              const float* __restrict__ Bb,
                                              float* __restrict__ Out) {
  __shared__ float obuf[32][264];   // pad 8 floats

  const int tid = threadIdx.x;
  const int w   = tid >> 6;
  const int l   = tid & 63;
  const int g   = w >> 1;
  const int ohh = (w & 1) * 32;
  const int r0  = blockIdx.x * 32;
  const int ob  = blockIdx.y * 64;
  const int l15 = l & 15;
  const int oct = l >> 4;

  float4_t acc[2][2];
#pragma unroll
  for (int i = 0; i < 2; ++i)
#pragma unroll
    for (int j = 0; j < 2; ++j) acc[i][j] = (float4_t){0.f, 0.f, 0.f, 0.f};

#pragma unroll
  for (int ks = 0; ks < 2; ++ks) {
    short8_t af[2], bf[2];
#pragma unroll
    for (int mi = 0; mi < 2; ++mi)
      af[mi] = *(const short8_t*)(Hd + (size_t)(r0 + mi * 16 + l15) * 256 +
                                  g * 64 + ks * 32 + oct * 8);
#pragma unroll
    for (int ni = 0; ni < 2; ++ni)
      bf[ni] = *(const short8_t*)(W4t + (size_t)(g * 1024 + ob + ohh + ni * 16 + l15) * 64 +
                                  ks * 32 + oct * 8);
#pragma unroll
    for (int mi = 0; mi < 2; ++mi)
#pragma unroll
      for (int ni = 0; ni < 2; ++ni)
        acc[mi][ni] = __builtin_amdgcn_mfma_f32_16x16x32_bf16(af[mi], bf[ni], acc[mi][ni], 0, 0, 0);
  }

  // acc -> obuf (interleave groups), then coalesced float4 rows
#pragma unroll
  for (int ni = 0; ni < 2; ++ni) {
    const int lo = ohh + ni * 16 + l15;          // 0..63 within block's o range
    const float b = Bb[g * 1024 + ob + lo];
#pragma unroll
    for (int mi = 0; mi < 2; ++mi) {
      const int rloc = mi * 16 + oct * 4;
#pragma unroll
      for (int j = 0; j < 4; ++j)
        obuf[rloc + j][4 * lo + g] = acc[mi][ni][j] + b;
    }
  }
  __syncthreads();

#pragma unroll
  for (int i = 0; i < 4; ++i) {
    const int q = tid + i * 512;                  // 2048 float4 slots
    const int row = q >> 6, c4 = q & 63;
    const float4 v = *(const float4*)&obuf[row][c4 * 4];
    *(float4*)(Out + (size_t)(r0 + row) * OBS + 4 * ob + c4 * 4) = v;
  }
}

extern "C" void kernel_launch(void* const* d_in, const int* in_sizes, int n_in,
                              void* d_out, int out_size, void* d_ws, size_t ws_size,
                              hipStream_t stream) {
  const float* X          = (const float*)d_in[0];
  const float* eps        = (const float*)d_in[1];
  const int*   subset_idx = (const int*)  d_in[2];
  const float* enc_w1     = (const float*)d_in[3];
  const float* enc_b1     = (const float*)d_in[4];
  const float* enc_w2     = (const float*)d_in[5];
  const float* enc_b2     = (const float*)d_in[6];
  const float* dec_w1     = (const float*)d_in[7];
  const float* dec_b1     = (const float*)d_in[8];
  const float* dec_w2     = (const float*)d_in[9];
  const float* dec_b2     = (const float*)d_in[10];
  float* out = (float*)d_out;

  char* wsb = (char*)d_ws;
  unsigned short* Hbf = (unsigned short*)wsb;                  // 8 MB
  float*          z   = (float*)(wsb + (8u  << 20));           // 2 MB
  unsigned short* Hd  = (unsigned short*)(wsb + (10u << 20));  // 4 MB
  unsigned short* W1t = (unsigned short*)(wsb + (14u << 20));  // 1 MB
  unsigned short* W2t = (unsigned short*)(wsb + (15u << 20));  // 128 KB
  unsigned short* W4t = (unsigned short*)(wsb + (15u << 20) + (512u << 10)); // 512 KB

  prep_w1t<<<2048, 256, 0, stream>>>(enc_w1, W1t);
  prep_w2t<<<256,  256, 0, stream>>>(enc_w2, W2t);
  prep_w4t<<<1024, 256, 0, stream>>>(dec_w2, W4t);
  k_enc1<<<256, 512, 0, stream>>>(X, W1t, enc_b1, Hbf);
  k_enc2_samp<<<256, 512, 0, stream>>>(Hbf, W2t, enc_b2, eps, subset_idx, z);
  k_dec1<<<512, 256, 0, stream>>>(z, dec_w1, dec_b1, Hd);
  k_dec2<<<dim3(256, 16), 512, 0, stream>>>(Hd, W4t, dec_b2, out);
}

// Round 4
// 127.282 us; speedup vs baseline: 6.1173x; 1.1324x over previous
//
#include <hip/hip_runtime.h>
#include <hip/hip_bf16.h>
#include <math.h>

#define B_TOT 8192
#define OBS   4096
#define NG    4
#define GSZ   1024
#define LATD  64
#define HDIM  128

typedef __attribute__((ext_vector_type(8))) short   short8_t;
typedef __attribute__((ext_vector_type(8))) unsigned short ushort8_t;
typedef __attribute__((ext_vector_type(4))) float   float4_t;

__constant__ int kMask[15] = {1,2,4,8, 3,5,9,6,10,12, 7,11,13,14, 15};

static __device__ __forceinline__ unsigned short f2b(float x) {
  __hip_bfloat16 b = __float2bfloat16(x);
  return *reinterpret_cast<unsigned short*>(&b);
}
static __device__ __forceinline__ unsigned int pack2(float lo, float hi) {
  return (unsigned int)f2b(lo) | ((unsigned int)f2b(hi) << 16);
}

// ---------------- fused weight prep: transpose + bf16 ----------------------
// W1t[(g*128+h)*1024+k]=enc_w1[g][k][h]; W2t[(g*128+o)*128+k]=enc_w2[g][k][o];
// W4t[(g*1024+o)*64+k]=dec_w2[g][k][o]
#define N1 524288
#define N2 65536
#define N4 262144
__global__ __launch_bounds__(256) void k_prep(const float* __restrict__ w1,
                                              const float* __restrict__ w2,
                                              const float* __restrict__ w4,
                                              unsigned short* __restrict__ W1t,
                                              unsigned short* __restrict__ W2t,
                                              unsigned short* __restrict__ W4t) {
  const int i = blockIdx.x * 256 + threadIdx.x;
  if (i < N1) {
    const int g = i >> 17, rem = i & 131071;
    const int h = rem >> 10, k = rem & 1023;
    W1t[i] = f2b(w1[g * 131072 + k * 128 + h]);
  } else if (i < N1 + N2) {
    const int idx = i - N1;
    const int g = idx >> 14, rem = idx & 16383;
    const int o = rem >> 7, k = rem & 127;
    W2t[idx] = f2b(w2[g * 16384 + k * 128 + o]);
  } else {
    const int idx = i - N1 - N2;
    const int g = idx >> 16, rem = idx & 65535;
    const int o = rem >> 6, k = rem & 63;
    W4t[idx] = f2b(w4[g * 65536 + k * 1024 + o]);
  }
}

// ---------------- enc1: Hbf = relu(Xg @ enc_w1 + b1), bf16 out -------------
// 256 blocks x 512 thr. Block: 32 rows x 512 cols. Wave: g=w>>1, hh=(w&1)*64.
// K chunked 8 x 128 (4 MFMA sub-steps of 32). Single LDS buffer, 2 barriers
// per chunk; X prefetched into an 8xfloat4 register queue issued right after
// the first barrier so HBM latency hides under the chunk's compute.
__global__ __launch_bounds__(512, 2) void k_enc1(const float* __restrict__ X,
                                                 const unsigned short* __restrict__ W1t,
                                                 const float* __restrict__ B1,
                                                 unsigned short* __restrict__ Hbf) {
  __shared__ unsigned short lA[4][4][32][40];   // [sub][g][row][32k + 8 pad]

  const int tid = threadIdx.x;
  const int w   = tid >> 6;
  const int l   = tid & 63;
  const int g   = w >> 1;
  const int hh  = (w & 1) * 64;
  const int r0b = blockIdx.x * 32;
  const int l15 = l & 15;
  const int oct = l >> 4;

  const int sr  = tid >> 4;          // stage row 0..31
  const int skk = tid & 15;          // 8-float chunk 0..15

  const float* xrow = X + (size_t)(r0b + sr) * OBS;

  float4 q[4][2];
  // prologue: load chunk 0
#pragma unroll
  for (int sub = 0; sub < 4; ++sub) {
    const float* p = xrow + sub * 128 + skk * 8;
    q[sub][0] = *(const float4*)(p);
    q[sub][1] = *(const float4*)(p + 4);
  }

  float4_t acc[2][4];
#pragma unroll
  for (int i = 0; i < 2; ++i)
#pragma unroll
    for (int j = 0; j < 4; ++j) acc[i][j] = (float4_t){0.f, 0.f, 0.f, 0.f};

  for (int c = 0; c < 8; ++c) {
    // pack + write staged chunk to LDS
#pragma unroll
    for (int sub = 0; sub < 4; ++sub) {
      const float a0[4] = {q[sub][0].x, q[sub][0].y, q[sub][0].z, q[sub][0].w};
      const float a1[4] = {q[sub][1].x, q[sub][1].y, q[sub][1].z, q[sub][1].w};
#pragma unroll
      for (int gg = 0; gg < 4; ++gg)
        *(unsigned int*)(&lA[sub][gg][sr][skk * 2]) = pack2(a0[gg], a1[gg]);
    }
    __syncthreads();

    // issue next chunk's X loads now; latency hides under compute below
    if (c < 7) {
      const float* base = xrow + (c + 1) * 512;
#pragma unroll
      for (int sub = 0; sub < 4; ++sub) {
        const float* p = base + sub * 128 + skk * 8;
        q[sub][0] = *(const float4*)(p);
        q[sub][1] = *(const float4*)(p + 4);
      }
    }

#pragma unroll
    for (int sub = 0; sub < 4; ++sub) {
      short8_t af[2], bf[4];
#pragma unroll
      for (int mi = 0; mi < 2; ++mi)
        af[mi] = *(const short8_t*)((const char*)&lA[sub][g][0][0] +
                                    (mi * 16 + l15) * 80 + oct * 16);
#pragma unroll
      for (int ni = 0; ni < 4; ++ni)
        bf[ni] = *(const short8_t*)(W1t +
                  (size_t)(g * 128 + hh + ni * 16 + l15) * 1024 +
                  c * 128 + sub * 32 + oct * 8);
#pragma unroll
      for (int mi = 0; mi < 2; ++mi)
#pragma unroll
        for (int ni = 0; ni < 4; ++ni)
          acc[mi][ni] = __builtin_amdgcn_mfma_f32_16x16x32_bf16(af[mi], bf[ni], acc[mi][ni], 0, 0, 0);
    }
    __syncthreads();
  }

#pragma unroll
  for (int ni = 0; ni < 4; ++ni) {
    const int col = g * 128 + hh + ni * 16 + l15;
    const float b = B1[col];
#pragma unroll
    for (int mi = 0; mi < 2; ++mi) {
      const int rbase = r0b + mi * 16 + oct * 4;
#pragma unroll
      for (int j = 0; j < 4; ++j)
        Hbf[(size_t)(rbase + j) * 512 + col] = f2b(fmaxf(acc[mi][ni][j] + b, 0.0f));
    }
  }
}

// ------------- enc2 (MFMA, direct-global B) + PoE sampling -----------------
// 256 blocks x 512 thr. Block: 32 rows x 512 cols. A staged once; K-loop has
// NO barriers (B frags direct from L2-resident W2t).
struct Enc2Lds {
  union {
    unsigned short A[16][1288];   // plane = (ks*4+g): [row*40 + koff], +8 pad
    float mls[32][516];
  };
};
__global__ __launch_bounds__(512, 2) void k_enc2_samp(const unsigned short* __restrict__ Hbf,
                                                      const unsigned short* __restrict__ W2t,
                                                      const float* __restrict__ B2,
                                                      const float* __restrict__ eps,
                                                      const int*   __restrict__ subset_idx,
                                                      float* __restrict__ Z) {
  __shared__ Enc2Lds u;
  const int tid = threadIdx.x;
  const int w   = tid >> 6;
  const int l   = tid & 63;
  const int g   = w >> 1;
  const int hh  = (w & 1) * 64;
  const int rb  = blockIdx.x * 32;
  const int l15 = l & 15;
  const int oct = l >> 4;

  // stage A: Hbf[rb..rb+31][0..511] -> plane-partitioned layout
#pragma unroll
  for (int i = 0; i < 4; ++i) {
    const int q   = tid + i * 512;
    const int row = q >> 6;
    const int co  = (q & 63) * 8;          // 0..504
    const int gg  = co >> 7;
    const int cg  = co & 127;
    const int ks  = cg >> 5;
    const int off = cg & 31;
    const ushort8_t v = *(const ushort8_t*)(Hbf + (size_t)(rb + row) * 512 + co);
    *(ushort8_t*)(&u.A[ks * 4 + gg][row * 40 + off]) = v;
  }
  __syncthreads();

  float4_t acc[2][4];
#pragma unroll
  for (int i = 0; i < 2; ++i)
#pragma unroll
    for (int j = 0; j < 4; ++j) acc[i][j] = (float4_t){0.f, 0.f, 0.f, 0.f};

#pragma unroll
  for (int ks = 0; ks < 4; ++ks) {
    short8_t af[2], bf[4];
#pragma unroll
    for (int mi = 0; mi < 2; ++mi)
      af[mi] = *(const short8_t*)(&u.A[ks * 4 + g][(mi * 16 + l15) * 40 + oct * 8]);
#pragma unroll
    for (int ni = 0; ni < 4; ++ni)
      bf[ni] = *(const short8_t*)(W2t +
                (size_t)(g * 128 + hh + ni * 16 + l15) * 128 + ks * 32 + oct * 8);
#pragma unroll
    for (int mi = 0; mi < 2; ++mi)
#pragma unroll
      for (int ni = 0; ni < 4; ++ni)
        acc[mi][ni] = __builtin_amdgcn_mfma_f32_16x16x32_bf16(af[mi], bf[ni], acc[mi][ni], 0, 0, 0);
  }
  __syncthreads();   // done reading A; mls overlays it

#pragma unroll
  for (int ni = 0; ni < 4; ++ni) {
    const int col = g * 128 + hh + ni * 16 + l15;
    const float b = B2[col];
#pragma unroll
    for (int mi = 0; mi < 2; ++mi)
#pragma unroll
      for (int j = 0; j < 4; ++j)
        u.mls[mi * 16 + oct * 4 + j][col] = acc[mi][ni][j] + b;
  }
  __syncthreads();

  // PoE + reparameterize: 32 rows x 64 latents
#pragma unroll
  for (int q = 0; q < 4; ++q) {
    const int idx = q * 512 + tid;
    const int r   = idx >> 6;
    const int ll  = idx & 63;
    const int m   = kMask[subset_idx[rb + r]];
    float tau = 1.0f, num = 0.0f;
#pragma unroll
    for (int gg = 0; gg < 4; ++gg) {
      if (m & (1 << gg)) {
        const float lv = u.mls[r][gg * 128 + 64 + ll];
        const float mu = u.mls[r][gg * 128 + ll];
        const float t  = expf(-lv);
        tau += t;
        num = fmaf(t, mu, num);
      }
    }
    Z[(size_t)(rb + r) * LATD + ll] =
        num / tau + eps[(size_t)(rb + r) * LATD + ll] * rsqrtf(tau);
  }
}

// ---------------- dec1 (fp32 vector) -> hd bf16 ----------------------------
__global__ __launch_bounds__(256) void k_dec1(const float* __restrict__ Z,
                                              const float* __restrict__ W,
                                              const float* __restrict__ Bb,
                                              unsigned short* __restrict__ Hd) {
  const int tid  = threadIdx.x;
  const int wid  = tid >> 6;
  const int lane = tid & 63;
  const int r0   = blockIdx.x * 16 + wid * 4;
  const int c0   = lane * 4;
  const int g    = c0 >> 6;
  const int m0   = c0 & 63;

  const float* Wp = W + (size_t)g * LATD * LATD + m0;
  const float* Ap = Z + (size_t)r0 * LATD;

  float acc[4][4];
#pragma unroll
  for (int i = 0; i < 4; ++i)
#pragma unroll
    for (int j = 0; j < 4; ++j) acc[i][j] = 0.0f;

#pragma unroll 4
  for (int k = 0; k < LATD; ++k) {
    const float4 wv = *(const float4*)(Wp + (size_t)k * LATD);
    float a[4];
#pragma unroll
    for (int i = 0; i < 4; ++i) a[i] = Ap[(size_t)i * LATD + k];
#pragma unroll
    for (int i = 0; i < 4; ++i) {
      acc[i][0] = fmaf(a[i], wv.x, acc[i][0]);
      acc[i][1] = fmaf(a[i], wv.y, acc[i][1]);
      acc[i][2] = fmaf(a[i], wv.z, acc[i][2]);
      acc[i][3] = fmaf(a[i], wv.w, acc[i][3]);
    }
  }

  const float4 ba = *(const float4*)(Bb + c0);
#pragma unroll
  for (int i = 0; i < 4; ++i) {
    ushort4 o;
    o.x = f2b(fmaxf(acc[i][0] + ba.x, 0.0f));
    o.y = f2b(fmaxf(acc[i][1] + ba.y, 0.0f));
    o.z = f2b(fmaxf(acc[i][2] + ba.z, 0.0f));
    o.w = f2b(fmaxf(acc[i][3] + ba.w, 0.0f));
    *(ushort4*)(Hd + (size_t)(r0 + i) * 256 + c0) = o;
  }
}

// ---------------- dec2: direct-global MFMA + coalesced epilogue ------------
__global__ __launch_bounds__(512) void k_dec2(const unsigned short* __restrict__ Hd,
                                              const unsigned short* __restrict__ W4t,
                                              const float* __restrict__ Bb,
                                              float* __restrict__ Out) {
  __shared__ float obuf[32][264];

  const int tid = threadIdx.x;
  const int w   = tid >> 6;
  const int l   = tid & 63;
  const int g   = w >> 1;
  const int ohh = (w & 1) * 32;
  const int r0  = blockIdx.x * 32;
  const int ob  = blockIdx.y * 64;
  const int l15 = l & 15;
  const int oct = l >> 4;

  float4_t acc[2][2];
#pragma unroll
  for (int i = 0; i < 2; ++i)
#pragma unroll
    for (int j = 0; j < 2; ++j) acc[i][j] = (float4_t){0.f, 0.f, 0.f, 0.f};

#pragma unroll
  for (int ks = 0; ks < 2; ++ks) {
    short8_t af[2], bf[2];
#pragma unroll
    for (int mi = 0; mi < 2; ++mi)
      af[mi] = *(const short8_t*)(Hd + (size_t)(r0 + mi * 16 + l15) * 256 +
                                  g * 64 + ks * 32 + oct * 8);
#pragma unroll
    for (int ni = 0; ni < 2; ++ni)
      bf[ni] = *(const short8_t*)(W4t + (size_t)(g * 1024 + ob + ohh + ni * 16 + l15) * 64 +
                                  ks * 32 + oct * 8);
#pragma unroll
    for (int mi = 0; mi < 2; ++mi)
#pragma unroll
      for (int ni = 0; ni < 2; ++ni)
        acc[mi][ni] = __builtin_amdgcn_mfma_f32_16x16x32_bf16(af[mi], bf[ni], acc[mi][ni], 0, 0, 0);
  }

#pragma unroll
  for (int ni = 0; ni < 2; ++ni) {
    const int lo = ohh + ni * 16 + l15;
    const float b = Bb[g * 1024 + ob + lo];
#pragma unroll
    for (int mi = 0; mi < 2; ++mi) {
      const int rloc = mi * 16 + oct * 4;
#pragma unroll
      for (int j = 0; j < 4; ++j)
        obuf[rloc + j][4 * lo + g] = acc[mi][ni][j] + b;
    }
  }
  __syncthreads();

#pragma unroll
  for (int i = 0; i < 4; ++i) {
    const int q = tid + i * 512;
    const int row = q >> 6, c4 = q & 63;
    const float4 v = *(const float4*)&obuf[row][c4 * 4];
    *(float4*)(Out + (size_t)(r0 + row) * OBS + 4 * ob + c4 * 4) = v;
  }
}

extern "C" void kernel_launch(void* const* d_in, const int* in_sizes, int n_in,
                              void* d_out, int out_size, void* d_ws, size_t ws_size,
                              hipStream_t stream) {
  const float* X          = (const float*)d_in[0];
  const float* eps        = (const float*)d_in[1];
  const int*   subset_idx = (const int*)  d_in[2];
  const float* enc_w1     = (const float*)d_in[3];
  const float* enc_b1     = (const float*)d_in[4];
  const float* enc_w2     = (const float*)d_in[5];
  const float* enc_b2     = (const float*)d_in[6];
  const float* dec_w1     = (const float*)d_in[7];
  const float* dec_b1     = (const float*)d_in[8];
  const float* dec_w2     = (const float*)d_in[9];
  const float* dec_b2     = (const float*)d_in[10];
  float* out = (float*)d_out;

  char* wsb = (char*)d_ws;
  unsigned short* Hbf = (unsigned short*)wsb;                  // 8 MB
  float*          z   = (float*)(wsb + (8u  << 20));           // 2 MB
  unsigned short* Hd  = (unsigned short*)(wsb + (10u << 20));  // 4 MB
  unsigned short* W1t = (unsigned short*)(wsb + (14u << 20));  // 1 MB
  unsigned short* W2t = (unsigned short*)(wsb + (15u << 20));  // 128 KB
  unsigned short* W4t = (unsigned short*)(wsb + (15u << 20) + (512u << 10)); // 512 KB

  k_prep<<<3328, 256, 0, stream>>>(enc_w1, enc_w2, dec_w2, W1t, W2t, W4t);
  k_enc1<<<256, 512, 0, stream>>>(X, W1t, enc_b1, Hbf);
  k_enc2_samp<<<256, 512, 0, stream>>>(Hbf, W2t, enc_b2, eps, subset_idx, z);
  k_dec1<<<512, 256, 0, stream>>>(z, dec_w1, dec_b1, Hd);
  k_dec2<<<dim3(256, 16), 512, 0, stream>>>(Hd, W4t, dec_b2, out);
}